// Round 2
// baseline (3509.468 us; speedup 1.0000x reference)
//
#include <hip/hip_runtime.h>

// ---- problem constants ----
#define T_STEPS 4
#define BATCH   32
#define C_DIM   512
#define CH_DIM  2048
#define N_DIM   196
#define COLS    (BATCH * N_DIM)   // 6272 = 98 * 64 exactly
#define HEADS   8
#define CHD     64

// ---- tiles ----
#define BO 64
#define BN 64
#define BK 16

struct P {
    const float *x;
    const float *q_w, *q_bn_s, *q_bn_b;
    const float *k_w, *k_bn_s, *k_bn_b;
    const float *proj_w, *proj_b, *proj_bn_s, *proj_bn_b;
    const float *mlp1_w, *mlp1_b, *mlp1_bn_s, *mlp1_bn_b;
    const float *mlp2_w, *mlp2_b, *mlp2_bn_s, *mlp2_bn_b;
    float *v_q, *v_k, *v_y, *v_h1, *v_h2, *v_attn;
    unsigned char *q_sp, *k_sp, *y_sp, *h1_sp, *attn_sp;
    float *out;
    int t;
    int is_t0;
};

// Exact-f32 LIF step matching the reference's op-by-op rounding:
// v' = v + (z - v)/2 ; spike = (v' >= vth); hard reset.
__device__ __forceinline__ float lif_step(float z, float v_old, float vth, int& sp) {
    float d = __fsub_rn(z, v_old);
    float h = __fmul_rn(d, 0.5f);   // /2.0 == *0.5 bitwise
    float v = __fadd_rn(v_old, h);
    sp = (v >= vth) ? 1 : 0;
    return sp ? 0.0f : v;           // v*(1-spike) with spike in {0,1} exactly
}

// One fused GEMM + BN + LIF-step kernel, templated by stage.
// Accumulation over c is STRICTLY SEQUENTIAL (c=0..K-1), single f32 accumulator
// per output, unfused mul+add (except exact binary-input products -> fma OK).
// MODE 0: q&k stacked (O=1024, K=512), input = x[t]
// MODE 1: proj (O=512, K=512), input = k_sp * attn_sp (binary -> fma exact)
// MODE 2: mlp1 (O=2048, K=512), input = x[t] + y_sp (rounded f32 add)
// MODE 3: mlp2 (O=512, K=2048), input = h1_sp (binary -> fma exact); writes out
template <int MODE>
__global__ __launch_bounds__(256) void gemm_lif(P p) {
    constexpr int K_TOT = (MODE == 3) ? 2048 : 512;

    __shared__ float As[BO][BK + 1];
    __shared__ float Xs[BK][BN + 1];

    const int tid = threadIdx.x;
    const int tx = tid & 15;         // n-group
    const int ty = tid >> 4;         // o-group
    const int m0 = blockIdx.x * BN;  // column tile (b,n flattened)
    const int o0 = blockIdx.y * BO;  // output-channel tile
    const int t = p.t;

    float acc[4][4];
#pragma unroll
    for (int i = 0; i < 4; ++i)
#pragma unroll
        for (int j = 0; j < 4; ++j) acc[i][j] = 0.0f;

    for (int c0 = 0; c0 < K_TOT; c0 += BK) {
        // stage A tile: 64x16 weights
#pragma unroll
        for (int r = 0; r < 4; ++r) {
            int idx = tid + r * 256;
            int ol = idx >> 4, cl = idx & 15;
            int o = o0 + ol, c = c0 + cl;
            float w;
            if (MODE == 0)      w = (o < 512) ? p.q_w[o * 512 + c] : p.k_w[(o - 512) * 512 + c];
            else if (MODE == 1) w = p.proj_w[o * 512 + c];
            else if (MODE == 2) w = p.mlp1_w[o * 512 + c];
            else                w = p.mlp2_w[(size_t)o * 2048 + c];
            As[ol][cl] = w;
        }
        // stage X tile: 16x64 activations
#pragma unroll
        for (int r = 0; r < 4; ++r) {
            int idx = tid + r * 256;
            int cl = idx >> 6, nl = idx & 63;
            int m = m0 + nl;
            int b = m / N_DIM, n = m % N_DIM;
            int c = c0 + cl;
            float v;
            if (MODE == 0) {
                v = p.x[(((size_t)t * BATCH + b) * C_DIM + c) * N_DIM + n];
            } else if (MODE == 1) {
                float ks = (float)p.k_sp[((size_t)b * C_DIM + c) * N_DIM + n];
                float at = (float)p.attn_sp[((size_t)b * HEADS + (c >> 6)) * N_DIM + n];
                v = ks * at;   // {0,1}*{0,1}: exact
            } else if (MODE == 2) {
                float xo = p.x[(((size_t)t * BATCH + b) * C_DIM + c) * N_DIM + n];
                float ys = (float)p.y_sp[((size_t)b * C_DIM + c) * N_DIM + n];
                v = __fadd_rn(xo, ys);   // residual, rounded f32 like ref
            } else {
                v = (float)p.h1_sp[((size_t)b * CH_DIM + c) * N_DIM + n];
            }
            Xs[cl][nl] = v;
        }
        __syncthreads();

#pragma unroll
        for (int kk = 0; kk < BK; ++kk) {
            float a[4], xx[4];
#pragma unroll
            for (int i = 0; i < 4; ++i) a[i] = As[ty * 4 + i][kk];
#pragma unroll
            for (int j = 0; j < 4; ++j) xx[j] = Xs[kk][tx * 4 + j];
#pragma unroll
            for (int i = 0; i < 4; ++i)
#pragma unroll
                for (int j = 0; j < 4; ++j) {
                    if (MODE == 1 || MODE == 3) {
                        // product is exact (binary operand) -> fma == mul+add bitwise
                        acc[i][j] = __fmaf_rn(a[i], xx[j], acc[i][j]);
                    } else {
                        acc[i][j] = __fadd_rn(acc[i][j], __fmul_rn(a[i], xx[j]));
                    }
                }
        }
        __syncthreads();
    }

    // epilogue: BN + LIF step, exact f32 op order of the reference
#pragma unroll
    for (int i = 0; i < 4; ++i) {
#pragma unroll
        for (int j = 0; j < 4; ++j) {
            int o = o0 + ty * 4 + i;
            int m = m0 + tx * 4 + j;
            int b = m / N_DIM, n = m % N_DIM;
            float pre = acc[i][j];

            if (MODE == 0) {
                int oo;
                const float *bs, *bb;
                float *vbuf;
                unsigned char *sbuf;
                if (o < 512) { oo = o;       bs = p.q_bn_s; bb = p.q_bn_b; vbuf = p.v_q; sbuf = p.q_sp; }
                else         { oo = o - 512; bs = p.k_bn_s; bb = p.k_bn_b; vbuf = p.v_k; sbuf = p.k_sp; }
                float z = __fadd_rn(__fmul_rn(pre, bs[oo]), bb[oo]);
                size_t idx = ((size_t)b * C_DIM + oo) * N_DIM + n;
                float v = p.is_t0 ? 0.0f : vbuf[idx];
                int sp;
                v = lif_step(z, v, 1.0f, sp);
                vbuf[idx] = v;
                sbuf[idx] = (unsigned char)sp;
            } else if (MODE == 1) {
                float pp = __fadd_rn(pre, p.proj_b[o]);
                float z = __fadd_rn(__fmul_rn(pp, p.proj_bn_s[o]), p.proj_bn_b[o]);
                size_t idx = ((size_t)b * C_DIM + o) * N_DIM + n;
                float v = p.is_t0 ? 0.0f : p.v_y[idx];
                int sp;
                v = lif_step(z, v, 1.0f, sp);
                p.v_y[idx] = v;
                p.y_sp[idx] = (unsigned char)sp;
            } else if (MODE == 2) {
                float pp = __fadd_rn(pre, p.mlp1_b[o]);
                float z = __fadd_rn(__fmul_rn(pp, p.mlp1_bn_s[o]), p.mlp1_bn_b[o]);
                size_t idx = ((size_t)b * CH_DIM + o) * N_DIM + n;
                float v = p.is_t0 ? 0.0f : p.v_h1[idx];
                int sp;
                v = lif_step(z, v, 1.0f, sp);
                p.v_h1[idx] = v;
                p.h1_sp[idx] = (unsigned char)sp;
            } else {
                float pp = __fadd_rn(pre, p.mlp2_b[o]);
                float z = __fadd_rn(__fmul_rn(pp, p.mlp2_bn_s[o]), p.mlp2_bn_b[o]);
                size_t idx = ((size_t)b * C_DIM + o) * N_DIM + n;
                float v = p.is_t0 ? 0.0f : p.v_h2[idx];
                int sp;
                v = lif_step(z, v, 1.0f, sp);
                p.v_h2[idx] = v;
                size_t xi = (((size_t)t * BATCH + b) * C_DIM + o) * N_DIM + n;
                float xr = __fadd_rn(p.x[xi], (float)p.y_sp[idx]);   // x + y (ref rounding)
                p.out[xi] = __fadd_rn(xr, (float)sp);                // + h2
            }
        }
    }
}

// attention LIF: per (b,h,n) sum 64 q-spikes (integer-exact), LIF v_th=0.5
__global__ __launch_bounds__(256) void attn_lif(P p) {
    int i = blockIdx.x * blockDim.x + threadIdx.x;  // exactly 196*256 = 50176
    int n = i % N_DIM;
    int bh = i / N_DIM;
    int h = bh % HEADS;
    int b = bh / HEADS;
    int s = 0;
#pragma unroll 8
    for (int d = 0; d < CHD; ++d)
        s += p.q_sp[((size_t)b * C_DIM + h * CHD + d) * N_DIM + n];
    float v = p.is_t0 ? 0.0f : p.v_attn[i];
    int sp;
    v = lif_step((float)s, v, 0.5f, sp);   // dyadic-exact in f32
    p.v_attn[i] = v;
    p.attn_sp[i] = (unsigned char)sp;
}

extern "C" void kernel_launch(void* const* d_in, const int* in_sizes, int n_in,
                              void* d_out, int out_size, void* d_ws, size_t ws_size,
                              hipStream_t stream) {
    P p;
    p.x        = (const float*)d_in[0];
    p.q_w      = (const float*)d_in[1];
    p.q_bn_s   = (const float*)d_in[2];
    p.q_bn_b   = (const float*)d_in[3];
    p.k_w      = (const float*)d_in[4];
    p.k_bn_s   = (const float*)d_in[5];
    p.k_bn_b   = (const float*)d_in[6];
    p.proj_w   = (const float*)d_in[7];
    p.proj_b   = (const float*)d_in[8];
    p.proj_bn_s= (const float*)d_in[9];
    p.proj_bn_b= (const float*)d_in[10];
    p.mlp1_w   = (const float*)d_in[11];
    p.mlp1_b   = (const float*)d_in[12];
    p.mlp1_bn_s= (const float*)d_in[13];
    p.mlp1_bn_b= (const float*)d_in[14];
    p.mlp2_w   = (const float*)d_in[15];
    p.mlp2_b   = (const float*)d_in[16];
    p.mlp2_bn_s= (const float*)d_in[17];
    p.mlp2_bn_b= (const float*)d_in[18];
    p.out = (float*)d_out;

    char* ws = (char*)d_ws;
    size_t off = 0;
    auto alloc = [&](size_t bytes) -> void* {
        void* r = ws + off;
        off += (bytes + 255) & ~(size_t)255;
        return r;
    };
    const size_t E_C  = (size_t)BATCH * C_DIM * N_DIM;   // 3,211,264
    const size_t E_CH = (size_t)BATCH * CH_DIM * N_DIM;  // 12,845,056
    const size_t E_A  = (size_t)BATCH * HEADS * N_DIM;   // 50,176

    p.v_q    = (float*)alloc(E_C * 4);
    p.v_k    = (float*)alloc(E_C * 4);
    p.v_y    = (float*)alloc(E_C * 4);
    p.v_h2   = (float*)alloc(E_C * 4);
    p.v_h1   = (float*)alloc(E_CH * 4);
    p.v_attn = (float*)alloc(E_A * 4);
    p.q_sp   = (unsigned char*)alloc(E_C);
    p.k_sp   = (unsigned char*)alloc(E_C);
    p.y_sp   = (unsigned char*)alloc(E_C);
    p.h1_sp  = (unsigned char*)alloc(E_CH);
    p.attn_sp= (unsigned char*)alloc(E_A);

    const int n_tiles = COLS / BN;  // 98
    for (int t = 0; t < T_STEPS; ++t) {
        p.t = t;
        p.is_t0 = (t == 0);
        gemm_lif<0><<<dim3(n_tiles, 1024 / BO), 256, 0, stream>>>(p);  // q,k
        attn_lif<<<dim3(E_A / 256), 256, 0, stream>>>(p);              // attn
        gemm_lif<1><<<dim3(n_tiles, 512 / BO), 256, 0, stream>>>(p);   // proj -> y
        gemm_lif<2><<<dim3(n_tiles, 2048 / BO), 256, 0, stream>>>(p);  // mlp1
        gemm_lif<3><<<dim3(n_tiles, 512 / BO), 256, 0, stream>>>(p);   // mlp2 -> out
    }
}

// Round 3
// 2852.543 us; speedup vs baseline: 1.2303x; 1.2303x over previous
//
#include <hip/hip_runtime.h>
#include <cstdint>

// ---- problem constants ----
#define NT  4
#define NB  32
#define NC  512
#define NCH 2048
#define NN  196
#define NM  (NB * NN)   // 6272 columns, = 98*64 = 196*32
#define NH  8

struct GP {
    const float *q_bn_s, *q_bn_b, *k_bn_s, *k_bn_b;
    const float *proj_b, *proj_bn_s, *proj_bn_b;
    const float *mlp1_b, *mlp1_bn_s, *mlp1_bn_b;
    const float *mlp2_b, *mlp2_bn_s, *mlp2_bn_b;
    const float *wqkT, *wprojT, *wmlp1T, *wmlp2T;  // [K][O] transposed weights
    const float *xT;                                // [T][C][M] permuted input
    float *xy;                                      // [C][M] x + y_spike (per t)
    float *v_q, *v_k, *v_y, *v_h1, *v_h2, *v_attn;  // LIF states, [C][M]
    unsigned char *q_sp, *k_sp, *x_one, *h1_sp, *attn_sp; // binary spikes
    float *out;
    int t;
};

// Exact-f32 LIF step (validated bitwise vs reference in R2).
__device__ __forceinline__ float lif_step(float z, float v_old, float vth, int& sp) {
    float d = __fsub_rn(z, v_old);
    float h = __fmul_rn(d, 0.5f);
    float v = __fadd_rn(v_old, h);
    sp = (v >= vth) ? 1 : 0;
    return sp ? 0.0f : v;
}

typedef const void __attribute__((address_space(1))) gas_t;
typedef void __attribute__((address_space(3))) las_t;
__device__ __forceinline__ void gl_lds16(const float* g, float* l) {
    // lane i: 16B from g(per-lane) -> ldsbase + i*16 (wave-uniform base)
    __builtin_amdgcn_global_load_lds((gas_t*)g, (las_t*)l, 16, 0, 0);
}

// ---------------- pre-kernels ----------------

// dst[c*ldD + offD + o] = src[o*K + c]   (32x32 LDS tiles)
__global__ __launch_bounds__(256) void trw_k(const float* __restrict__ src,
                                             float* __restrict__ dst,
                                             int K, int ldD, int offD) {
    __shared__ float tle[32][33];
    const int c0 = blockIdx.x * 32, o0 = blockIdx.y * 32;
    const int tx = threadIdx.x & 31, ty = threadIdx.x >> 5;  // ty: 0..7
#pragma unroll
    for (int r = 0; r < 4; ++r)
        tle[ty + r * 8][tx] = src[(size_t)(o0 + ty + r * 8) * K + c0 + tx];
    __syncthreads();
#pragma unroll
    for (int r = 0; r < 4; ++r)
        dst[(size_t)(c0 + ty + r * 8) * ldD + offD + o0 + tx] = tle[tx][ty + r * 8];
}

// xT[t][c][b][n] = x[t][b][c][n]
__global__ __launch_bounds__(64) void permx_k(const float* __restrict__ x,
                                              float* __restrict__ xT) {
    const int id = blockIdx.x;         // t*16384 + c*32 + b
    const int b = id & 31;
    const int c = (id >> 5) & 511;
    const int t = id >> 14;
    const float* s = x + ((size_t)(t * NB + b) * NC + c) * NN;
    float* d = xT + ((size_t)(t * NC + c) * NB + b) * NN;
    for (int n = threadIdx.x; n < NN; n += 64) d[n] = s[n];
}

// attn LIF: per (h,m): integer sum of 64 q-spike bytes; LIF vth=0.5
__global__ __launch_bounds__(256) void attn_k(GP gp) {
    const int m = blockIdx.x * 256 + threadIdx.x;
    const int h = blockIdx.y;
    if (m >= NM) return;
    const unsigned char* q = gp.q_sp + (size_t)h * 64 * NM + m;
    int s = 0;
#pragma unroll 8
    for (int d = 0; d < 64; ++d) s += q[(size_t)d * NM];
    float v = gp.t ? gp.v_attn[(size_t)h * NM + m] : 0.0f;
    int sp;
    v = lif_step((float)s, v, 0.5f, sp);
    gp.v_attn[(size_t)h * NM + m] = v;
    gp.attn_sp[(size_t)h * NM + m] = (unsigned char)sp;
}

// x_one = k_sp AND attn_sp  (binary product, exact)
__global__ __launch_bounds__(256) void xone_k(GP gp) {
    const int c = blockIdx.y;
    const int m4 = (blockIdx.x * 256 + threadIdx.x) * 4;
    if (m4 >= NM) return;
    const unsigned int kv = *(const unsigned int*)(gp.k_sp + (size_t)c * NM + m4);
    const unsigned int av = *(const unsigned int*)(gp.attn_sp + (size_t)(c >> 6) * NM + m4);
    *(unsigned int*)(gp.x_one + (size_t)c * NM + m4) = kv & av;
}

// ---------------- fused GEMM + BN + LIF ----------------
// MODE 0: q&k stacked (O=1024,K=512), X=xT[t]           unfused mul+add
// MODE 1: proj (O=512,K=512), X=x_one (binary u8)       fma
// MODE 2: mlp1 (O=2048,K=512), X=xy                     unfused mul+add
// MODE 3: mlp2 (O=512,K=2048), X=h1_sp (binary u8)      fma; writes out
// Single-wave blocks (64 thr), wave-private double-buffered LDS, NO barriers.
template <int MODE>
__global__ __launch_bounds__(64) void gemm_lif(GP gp) {
    constexpr bool FUSED = (MODE == 1 || MODE == 3);
    constexpr int K_TOT = (MODE == 3) ? 2048 : 512;
    constexpr int LDA = (MODE == 0) ? 1024 : (MODE == 2) ? 2048 : 512;
    constexpr int BK = FUSED ? 32 : 16;
    constexpr int RN = FUSED ? 4 : 8;
    constexpr int BN = FUSED ? 32 : 64;
    constexpr int XP = FUSED ? 40 : 64;   // fused Xs padded (reg-staged, pad OK)
    constexpr int NIT = K_TOT / BK;

    __shared__ float As[2][BK][64];
    __shared__ float Xs[2][BK][XP];

    const int tid = threadIdx.x;
    const int to = tid & 7;        // 8 o-groups (8 rows each)
    const int tn = tid >> 3;       // 8 n-groups (RN cols each)
    const int m0 = blockIdx.x * BN;
    const int o0 = blockIdx.y * 64;

    const float* wA = (MODE == 0) ? gp.wqkT : (MODE == 1) ? gp.wprojT
                    : (MODE == 2) ? gp.wmlp1T : gp.wmlp2T;
    const float* xf = (MODE == 0) ? gp.xT + (size_t)gp.t * NC * NM : gp.xy;
    const unsigned char* xu = (MODE == 1) ? gp.x_one : gp.h1_sp;

    uint4 xb = {0, 0, 0, 0};   // staged X bytes (fused)

    auto stage = [&](int buf, int c0) {
#pragma unroll
        for (int r = 0; r < BK / 4; ++r) {
            const float* g = wA + (size_t)(c0 + r * 4 + (tid >> 4)) * LDA + o0 + (tid & 15) * 4;
            gl_lds16(g, &As[buf][r * 4][0]);
        }
        if constexpr (!FUSED) {
#pragma unroll
            for (int r = 0; r < BK / 4; ++r) {
                const float* g = xf + (size_t)(c0 + r * 4 + (tid >> 4)) * NM + m0 + (tid & 15) * 4;
                gl_lds16(g, &Xs[buf][r * 4][0]);
            }
        } else {
            xb = *(const uint4*)(xu + (size_t)(c0 + (tid >> 1)) * NM + m0 + (tid & 1) * 16);
        }
    };

    auto xwrite = [&](int buf) {
        if constexpr (FUSED) {
            const int row = tid >> 1, cb = (tid & 1) * 16;
            float* d = &Xs[buf][row][cb];
            const unsigned int w[4] = {xb.x, xb.y, xb.z, xb.w};
#pragma unroll
            for (int q = 0; q < 4; ++q) {
                float4 f;
                f.x = (float)(unsigned char)(w[q]);
                f.y = (float)(unsigned char)(w[q] >> 8);
                f.z = (float)(unsigned char)(w[q] >> 16);
                f.w = (float)(w[q] >> 24);
                *(float4*)(d + q * 4) = f;
            }
        }
    };

    float acc[8][RN];
#pragma unroll
    for (int i = 0; i < 8; ++i)
#pragma unroll
        for (int j = 0; j < RN; ++j) acc[i][j] = 0.0f;

    stage(0, 0);
    asm volatile("s_waitcnt vmcnt(0)" ::: "memory");
    xwrite(0);

#pragma unroll 1
    for (int it = 0; it < NIT; ++it) {
        const int cur = it & 1;
        const bool more = (it + 1 < NIT);
        if (more) stage(cur ^ 1, (it + 1) * BK);

        const float* as = &As[cur][0][0];
        const float* xs = &Xs[cur][0][0];

        if constexpr (!FUSED) {
            float4 a0[2], a1[2], x0[2], x1[2];
            a0[0] = *(const float4*)(as + to * 8);
            a1[0] = *(const float4*)(as + to * 8 + 4);
            x0[0] = *(const float4*)(xs + tn * 8);
            x1[0] = *(const float4*)(xs + tn * 8 + 4);
#pragma unroll
            for (int kk = 0; kk < BK; ++kk) {
                const int s = kk & 1;
                if (kk + 1 < BK) {
                    const int ns = s ^ 1;
                    a0[ns] = *(const float4*)(as + (kk + 1) * 64 + to * 8);
                    a1[ns] = *(const float4*)(as + (kk + 1) * 64 + to * 8 + 4);
                    x0[ns] = *(const float4*)(xs + (kk + 1) * 64 + tn * 8);
                    x1[ns] = *(const float4*)(xs + (kk + 1) * 64 + tn * 8 + 4);
                }
                const float a[8] = {a0[s].x, a0[s].y, a0[s].z, a0[s].w,
                                    a1[s].x, a1[s].y, a1[s].z, a1[s].w};
                const float xr[8] = {x0[s].x, x0[s].y, x0[s].z, x0[s].w,
                                     x1[s].x, x1[s].y, x1[s].z, x1[s].w};
#pragma unroll
                for (int i = 0; i < 8; ++i)
#pragma unroll
                    for (int j = 0; j < 8; ++j)
                        acc[i][j] = __fadd_rn(acc[i][j], __fmul_rn(a[i], xr[j]));
            }
        } else {
            float4 a0[4], a1[4], x0[4];
#pragma unroll
            for (int p = 0; p < 2; ++p) {
                a0[p] = *(const float4*)(as + p * 64 + to * 8);
                a1[p] = *(const float4*)(as + p * 64 + to * 8 + 4);
                x0[p] = *(const float4*)(xs + p * XP + tn * 4);
            }
#pragma unroll
            for (int kk = 0; kk < BK; ++kk) {
                const int s = kk & 3;
                if (kk + 2 < BK) {
                    const int ps = (kk + 2) & 3;
                    a0[ps] = *(const float4*)(as + (kk + 2) * 64 + to * 8);
                    a1[ps] = *(const float4*)(as + (kk + 2) * 64 + to * 8 + 4);
                    x0[ps] = *(const float4*)(xs + (kk + 2) * XP + tn * 4);
                }
                const float a[8] = {a0[s].x, a0[s].y, a0[s].z, a0[s].w,
                                    a1[s].x, a1[s].y, a1[s].z, a1[s].w};
                const float xr[4] = {x0[s].x, x0[s].y, x0[s].z, x0[s].w};
#pragma unroll
                for (int i = 0; i < 8; ++i)
#pragma unroll
                    for (int j = 0; j < 4; ++j)
                        acc[i][j] = __fmaf_rn(a[i], xr[j], acc[i][j]);
            }
        }
        asm volatile("s_waitcnt vmcnt(0)" ::: "memory");
        if (more) xwrite(cur ^ 1);
    }

    // ---- epilogue: BN + LIF, exact reference op order ----
    const int mb = m0 + tn * RN;
    if constexpr (MODE == 0) {
        const bool isq = (o0 < NC);
        const float* bs = isq ? gp.q_bn_s : gp.k_bn_s;
        const float* bbv = isq ? gp.q_bn_b : gp.k_bn_b;
        float* vb = isq ? gp.v_q : gp.v_k;
        unsigned char* sb = isq ? gp.q_sp : gp.k_sp;
#pragma unroll
        for (int i = 0; i < 8; ++i) {
            const int oo = (o0 + to * 8 + i) & (NC - 1);
            const float sc = bs[oo], bc = bbv[oo];
            float* vr = vb + (size_t)oo * NM + mb;
            float vv[8];
            if (gp.t) {
                const float4 v0 = *(const float4*)vr, v1 = *(const float4*)(vr + 4);
                vv[0] = v0.x; vv[1] = v0.y; vv[2] = v0.z; vv[3] = v0.w;
                vv[4] = v1.x; vv[5] = v1.y; vv[6] = v1.z; vv[7] = v1.w;
            } else {
#pragma unroll
                for (int j = 0; j < 8; ++j) vv[j] = 0.0f;
            }
            unsigned int pk[2] = {0, 0};
#pragma unroll
            for (int j = 0; j < 8; ++j) {
                const float z = __fadd_rn(__fmul_rn(acc[i][j], sc), bc);
                int sp;
                vv[j] = lif_step(z, vv[j], 1.0f, sp);
                pk[j >> 2] |= (unsigned)sp << ((j & 3) * 8);
            }
            *(float4*)vr = make_float4(vv[0], vv[1], vv[2], vv[3]);
            *(float4*)(vr + 4) = make_float4(vv[4], vv[5], vv[6], vv[7]);
            *(unsigned int*)(sb + (size_t)oo * NM + mb) = pk[0];
            *(unsigned int*)(sb + (size_t)oo * NM + mb + 4) = pk[1];
        }
    } else if constexpr (MODE == 2) {
#pragma unroll
        for (int i = 0; i < 8; ++i) {
            const int o = o0 + to * 8 + i;
            const float bi = gp.mlp1_b[o], sc = gp.mlp1_bn_s[o], bc = gp.mlp1_bn_b[o];
            float* vr = gp.v_h1 + (size_t)o * NM + mb;
            float vv[8];
            if (gp.t) {
                const float4 v0 = *(const float4*)vr, v1 = *(const float4*)(vr + 4);
                vv[0] = v0.x; vv[1] = v0.y; vv[2] = v0.z; vv[3] = v0.w;
                vv[4] = v1.x; vv[5] = v1.y; vv[6] = v1.z; vv[7] = v1.w;
            } else {
#pragma unroll
                for (int j = 0; j < 8; ++j) vv[j] = 0.0f;
            }
            unsigned int pk[2] = {0, 0};
#pragma unroll
            for (int j = 0; j < 8; ++j) {
                const float z = __fadd_rn(__fmul_rn(__fadd_rn(acc[i][j], bi), sc), bc);
                int sp;
                vv[j] = lif_step(z, vv[j], 1.0f, sp);
                pk[j >> 2] |= (unsigned)sp << ((j & 3) * 8);
            }
            *(float4*)vr = make_float4(vv[0], vv[1], vv[2], vv[3]);
            *(float4*)(vr + 4) = make_float4(vv[4], vv[5], vv[6], vv[7]);
            *(unsigned int*)(gp.h1_sp + (size_t)o * NM + mb) = pk[0];
            *(unsigned int*)(gp.h1_sp + (size_t)o * NM + mb + 4) = pk[1];
        }
    } else if constexpr (MODE == 1) {
#pragma unroll
        for (int i = 0; i < 8; ++i) {
            const int o = o0 + to * 8 + i;
            const float bi = gp.proj_b[o], sc = gp.proj_bn_s[o], bc = gp.proj_bn_b[o];
            float* vr = gp.v_y + (size_t)o * NM + mb;
            const float4 vld = gp.t ? *(const float4*)vr : make_float4(0, 0, 0, 0);
            const float4 xv = *(const float4*)(gp.xT + ((size_t)gp.t * NC + o) * NM + mb);
            float vv[4] = {vld.x, vld.y, vld.z, vld.w};
            const float xvv[4] = {xv.x, xv.y, xv.z, xv.w};
            float xyo[4];
#pragma unroll
            for (int j = 0; j < 4; ++j) {
                const float z = __fadd_rn(__fmul_rn(__fadd_rn(acc[i][j], bi), sc), bc);
                int sp;
                vv[j] = lif_step(z, vv[j], 1.0f, sp);
                xyo[j] = __fadd_rn(xvv[j], (float)sp);   // residual x + y (ref rounding)
            }
            *(float4*)vr = make_float4(vv[0], vv[1], vv[2], vv[3]);
            *(float4*)(gp.xy + (size_t)o * NM + mb) = make_float4(xyo[0], xyo[1], xyo[2], xyo[3]);
        }
    } else {  // MODE 3
#pragma unroll
        for (int i = 0; i < 8; ++i) {
            const int o = o0 + to * 8 + i;
            const float bi = gp.mlp2_b[o], sc = gp.mlp2_bn_s[o], bc = gp.mlp2_bn_b[o];
            float* vr = gp.v_h2 + (size_t)o * NM + mb;
            const float4 vld = gp.t ? *(const float4*)vr : make_float4(0, 0, 0, 0);
            const float4 xyv = *(const float4*)(gp.xy + (size_t)o * NM + mb);
            float vv[4] = {vld.x, vld.y, vld.z, vld.w};
            const float xyf[4] = {xyv.x, xyv.y, xyv.z, xyv.w};
#pragma unroll
            for (int j = 0; j < 4; ++j) {
                const float z = __fadd_rn(__fmul_rn(__fadd_rn(acc[i][j], bi), sc), bc);
                int sp;
                vv[j] = lif_step(z, vv[j], 1.0f, sp);
                const int m = mb + j;
                const int b = m / NN;
                const int n = m - b * NN;
                gp.out[(((size_t)gp.t * NB + b) * NC + o) * NN + n] = __fadd_rn(xyf[j], (float)sp);
            }
            *(float4*)vr = make_float4(vv[0], vv[1], vv[2], vv[3]);
        }
    }
}

extern "C" void kernel_launch(void* const* d_in, const int* in_sizes, int n_in,
                              void* d_out, int out_size, void* d_ws, size_t ws_size,
                              hipStream_t stream) {
    const float* x       = (const float*)d_in[0];
    const float* q_w     = (const float*)d_in[1];
    const float* k_w     = (const float*)d_in[4];
    const float* proj_w  = (const float*)d_in[7];
    const float* mlp1_w  = (const float*)d_in[11];
    const float* mlp2_w  = (const float*)d_in[15];

    GP gp;
    gp.q_bn_s = (const float*)d_in[2];  gp.q_bn_b = (const float*)d_in[3];
    gp.k_bn_s = (const float*)d_in[5];  gp.k_bn_b = (const float*)d_in[6];
    gp.proj_b = (const float*)d_in[8];  gp.proj_bn_s = (const float*)d_in[9];  gp.proj_bn_b = (const float*)d_in[10];
    gp.mlp1_b = (const float*)d_in[12]; gp.mlp1_bn_s = (const float*)d_in[13]; gp.mlp1_bn_b = (const float*)d_in[14];
    gp.mlp2_b = (const float*)d_in[16]; gp.mlp2_bn_s = (const float*)d_in[17]; gp.mlp2_bn_b = (const float*)d_in[18];
    gp.out = (float*)d_out;

    char* ws = (char*)d_ws;
    size_t off = 0;
    auto alloc = [&](size_t bytes) -> void* {
        void* r = ws + off;
        off += (bytes + 255) & ~(size_t)255;
        return r;
    };
    float* wqkT   = (float*)alloc((size_t)512 * 1024 * 4);
    float* wprojT = (float*)alloc((size_t)512 * 512 * 4);
    float* wmlp1T = (float*)alloc((size_t)512 * 2048 * 4);
    float* wmlp2T = (float*)alloc((size_t)2048 * 512 * 4);
    float* xT     = (float*)alloc((size_t)NT * NC * NM * 4);
    gp.xy     = (float*)alloc((size_t)NC * NM * 4);
    gp.v_q    = (float*)alloc((size_t)NC * NM * 4);
    gp.v_k    = (float*)alloc((size_t)NC * NM * 4);
    gp.v_y    = (float*)alloc((size_t)NC * NM * 4);
    gp.v_h2   = (float*)alloc((size_t)NC * NM * 4);
    gp.v_h1   = (float*)alloc((size_t)NCH * NM * 4);
    gp.v_attn = (float*)alloc((size_t)NH * NM * 4);
    gp.q_sp   = (unsigned char*)alloc((size_t)NC * NM);
    gp.k_sp   = (unsigned char*)alloc((size_t)NC * NM);
    gp.x_one  = (unsigned char*)alloc((size_t)NC * NM);
    gp.h1_sp  = (unsigned char*)alloc((size_t)NCH * NM);
    gp.attn_sp= (unsigned char*)alloc((size_t)NH * NM);
    gp.wqkT = wqkT; gp.wprojT = wprojT; gp.wmlp1T = wmlp1T; gp.wmlp2T = wmlp2T;
    gp.xT = xT;

    // one-time (per call) layout transforms
    trw_k<<<dim3(16, 16), 256, 0, stream>>>(q_w,    wqkT,   512,  1024, 0);
    trw_k<<<dim3(16, 16), 256, 0, stream>>>(k_w,    wqkT,   512,  1024, 512);
    trw_k<<<dim3(16, 16), 256, 0, stream>>>(proj_w, wprojT, 512,  512,  0);
    trw_k<<<dim3(16, 64), 256, 0, stream>>>(mlp1_w, wmlp1T, 512,  2048, 0);
    trw_k<<<dim3(64, 16), 256, 0, stream>>>(mlp2_w, wmlp2T, 2048, 512,  0);
    permx_k<<<NT * NC * NB, 64, 0, stream>>>(x, xT);

    for (int t = 0; t < NT; ++t) {
        gp.t = t;
        gemm_lif<0><<<dim3(98, 16), 64, 0, stream>>>(gp);   // q,k
        attn_k<<<dim3(25, NH), 256, 0, stream>>>(gp);       // attn LIF
        xone_k<<<dim3(7, NC), 256, 0, stream>>>(gp);        // k_sp & attn_sp
        gemm_lif<1><<<dim3(196, 8), 64, 0, stream>>>(gp);   // proj -> v_y, xy
        gemm_lif<2><<<dim3(98, 32), 64, 0, stream>>>(gp);   // mlp1 -> h1_sp
        gemm_lif<3><<<dim3(196, 8), 64, 0, stream>>>(gp);   // mlp2 -> out
    }
}